// Round 30
// baseline (82.320 us; speedup 1.0000x reference)
//
#include <hip/hip_runtime.h>
#include <hip/hip_bf16.h>

#define D_MODEL 96
#define D_INNER 192
#define BATCH 32
#define HH 56
#define WW 56
#define NPIX (BATCH*HH*WW)   // 100352
#define LN_EPS 1e-5f
#define WSLAB 12288          // shorts per combined tap slab (96 oc * 128 pad)
#define WSLABB 24576         // bytes
#define K2_NWG 1568          // NPIX / 64 = 8 * 196 (bijective XCD swizzle)
#define K2_CPX 196

typedef unsigned short ushort_t;
typedef __attribute__((ext_vector_type(8))) short short8;   // 8 bf16 (4 VGPRs)
typedef __attribute__((ext_vector_type(4))) float f32x4;

// g_Wcomb[tap][oc][s]: combined (Wi_live @ Wc[tap]) bf16, 256-B rows,
// pre-swizzled by short-index XOR ((oc&7)<<3) (r27-verified).
// g_Bt[tap][oc] = b_in @ Wc[tap] (fp32).
__device__ __align__(16) ushort_t g_Wcomb[9 * WSLAB];
__device__ float g_Bt[9 * 96];

static __device__ __forceinline__ unsigned short f2bf(float f) {
    unsigned u = __float_as_uint(f);
    unsigned r = (u + 0x7fffu + ((u >> 16) & 1u)) >> 16;
    return (unsigned short)r;
}

// ---------------------------------------------------------------------------
// Kernel 0: weight fold (r29-verified: 4 independent accumulators, no Ball).
// ---------------------------------------------------------------------------
__global__ __launch_bounds__(256) void k0_wt(const float* __restrict__ Wc,
                                             const float* __restrict__ Wi,
                                             const float* __restrict__ b_in) {
    __shared__ float sWi[96 * 193];   // 74,112 B
    const int t = threadIdx.x;
    for (int i = t; i < 96 * 192; i += 256) {
        const int c = i / 192, j = i - c * 192;
        sWi[c * 193 + j] = Wi[c * 384 + j];
    }
    __syncthreads();

    const int o = blockIdx.x * 256 + t;
    if (o < 9 * WSLAB) {
        const int tap = o / WSLAB;
        const int rem = o - tap * WSLAB;
        const int oc = rem >> 7, s = rem & 127;
        const int sl = s ^ ((oc & 7) << 3);          // logical c index
        float acc = 0.f;
        if (sl < 96) {
            const float* wi = sWi + sl * 193;
            const float* wc = Wc + (size_t)tap * 18432 + oc;
            float a0 = 0.f, a1 = 0.f, a2 = 0.f, a3 = 0.f;
            #pragma unroll 8
            for (int j = 0; j < 192; j += 4) {
                a0 += wi[j + 0] * wc[(j + 0) * 96];
                a1 += wi[j + 1] * wc[(j + 1) * 96];
                a2 += wi[j + 2] * wc[(j + 2) * 96];
                a3 += wi[j + 3] * wc[(j + 3) * 96];
            }
            acc = (a0 + a1) + (a2 + a3);
        }
        g_Wcomb[o] = f2bf(acc);
    } else if (o < 9 * WSLAB + 864) {
        const int idx = o - 9 * WSLAB;
        const int tap = idx / 96, oc = idx - tap * 96;
        const float* wc = Wc + (size_t)tap * 18432 + oc;
        float a0 = 0.f, a1 = 0.f, a2 = 0.f, a3 = 0.f;
        #pragma unroll 8
        for (int j = 0; j < 192; j += 4) {
            a0 += b_in[j + 0] * wc[(j + 0) * 96];
            a1 += b_in[j + 1] * wc[(j + 1) * 96];
            a2 += b_in[j + 2] * wc[(j + 2) * 96];
            a3 += b_in[j + 3] * wc[(j + 3) * 96];
        }
        g_Bt[idx] = (a0 + a1) + (a2 + a3);
    }
}

// ---------------------------------------------------------------------------
// FUSED kernel: LN (halo recompute) + folded conv + bias + SiLU + residual.
// ROUND-30: weight slab DOUBLE-BUFFERED (sWs[2], 49.2 KB) -> ONE barrier
// per tap instead of two, and stageW(tap+1) issued BEFORE the tap's compute
// so the async copy rides under the full tap (r17-proven pattern).
// Write-after-read safety: stage(t+1) targets buf last read at tap t-1,
// whose readers were released by the barrier ending t-1 (before this issue).
// The end-of-tap __syncthreads drains vmcnt (slab t+1 complete) + orders
// reads. Everything else byte-identical to r29 (verified).
// ---------------------------------------------------------------------------
__global__ __launch_bounds__(128) void k_fused(
    const float* __restrict__ X, const float* __restrict__ ln_w,
    const float* __restrict__ ln_b, const float* __restrict__ conv_b,
    float* __restrict__ OUT)
{
    __shared__ ushort_t sH[100 * 128];    // 25,600 B halo h (swizzled rows)
    __shared__ ushort_t sWs[2][WSLAB];    // 49,152 B double-buffered slabs
    const int t = threadIdx.x;
    const int w = t >> 6, l = t & 63;
    const int lm = l & 15, lq = l >> 4;

    const int lb = ((int)blockIdx.x & 7) * K2_CPX + ((int)blockIdx.x >> 3);
    const int img = lb / 49, tile = lb - img * 49;
    const int ty = (tile / 7) * 8, tx = (tile % 7) * 8;
    const size_t imgbase = (size_t)img * 3136;

    // ---- W staging: linear async copy into slab buffer `buf` ----
    auto stageW = [&](int buf, int tap) {
        const char* g = (const char*)g_Wcomb + (size_t)tap * WSLABB + t * 16;
        char* d = (char*)&sWs[buf][0] + t * 16;
        #pragma unroll
        for (int j = 0; j < 12; ++j)
            __builtin_amdgcn_global_load_lds(
                (const __attribute__((address_space(1))) unsigned*)(g + j * 2048),
                (__attribute__((address_space(3))) unsigned*)(d + j * 2048),
                16, 0, 0);
    };
    stageW(0, 0);                        // overlaps Phase-1 LN

    // ================= Phase 1: LN halo -> swizzled sH ====================
    {
        const int g4 = t >> 2, tig = t & 3;
        #pragma unroll 1
        for (int it = 0; it < 4; ++it) {
            const int px = it * 32 + g4;
            if (px >= 100) continue;
            const int hr = px / 10, hc = px - hr * 10;
            const int gr = ty + hr - 1, gc = tx + hc - 1;
            const bool valid = gr >= 0 && gr < HH && gc >= 0 && gc < WW;
            const float* xp = X + (imgbase + gr * WW + gc) * 96 + tig * 24;
            uint4 out[3];
            if (valid) {
                float4 xq[6];
                float s = 0.f;
                #pragma unroll
                for (int c = 0; c < 6; ++c) {
                    xq[c] = *(const float4*)(xp + c * 4);
                    s += xq[c].x + xq[c].y + xq[c].z + xq[c].w;
                }
                s += __shfl_xor(s, 1, 4);
                s += __shfl_xor(s, 2, 4);
                const float mu = s * (1.f / 96.f);
                float v = 0.f;
                #pragma unroll
                for (int c = 0; c < 6; ++c) {
                    const float d0 = xq[c].x - mu, d1 = xq[c].y - mu;
                    const float d2 = xq[c].z - mu, d3 = xq[c].w - mu;
                    v += d0 * d0 + d1 * d1 + d2 * d2 + d3 * d3;
                }
                v += __shfl_xor(v, 1, 4);
                v += __shfl_xor(v, 2, 4);
                const float rs = rsqrtf(v * (1.f / 96.f) + LN_EPS);
                unsigned u[12];
                #pragma unroll
                for (int c = 0; c < 6; ++c) {
                    const float4 lw = *(const float4*)(ln_w + tig * 24 + c * 4);
                    const float4 lb2 = *(const float4*)(ln_b + tig * 24 + c * 4);
                    u[c * 2 + 0] = (unsigned)f2bf((xq[c].x - mu) * rs * lw.x + lb2.x)
                                 | ((unsigned)f2bf((xq[c].y - mu) * rs * lw.y + lb2.y) << 16);
                    u[c * 2 + 1] = (unsigned)f2bf((xq[c].z - mu) * rs * lw.z + lb2.z)
                                 | ((unsigned)f2bf((xq[c].w - mu) * rs * lw.w + lb2.w) << 16);
                }
                out[0] = make_uint4(u[0], u[1], u[2], u[3]);
                out[1] = make_uint4(u[4], u[5], u[6], u[7]);
                out[2] = make_uint4(u[8], u[9], u[10], u[11]);
            } else {
                out[0] = out[1] = out[2] = make_uint4(0u, 0u, 0u, 0u);
            }
            const int key = (px & 7) << 4;
            char* rowp = (char*)sH + px * 256;
            #pragma unroll
            for (int q = 0; q < 3; ++q)
                *(uint4*)(rowp + (((tig * 3 + q) * 16) ^ key)) = out[q];
        }
    }
    __syncthreads();   // sH written + tap-0 slab drained (vmcnt)

    // ========== Phase 2: conv main loop (dbuf slab, 1 barrier/tap) ========
    int pr[4], pc[4];
    #pragma unroll
    for (int i = 0; i < 4; ++i) {
        const int px = i * 16 + lm;
        pr[i] = px >> 3; pc[i] = px & 7;
    }

    f32x4 acc[4][3];
    const f32x4 zf = {0.f, 0.f, 0.f, 0.f};
    #pragma unroll
    for (int i = 0; i < 4; ++i)
        #pragma unroll
        for (int n = 0; n < 3; ++n) acc[i][n] = zf;

    const int bkey = (lm & 7) << 4;
    const int brow0 = (w * 48 + lm) * 256 + lq * 16;   // wave's oc base row

    #pragma unroll 1
    for (int tap = 0; tap < 9; ++tap) {
        if (tap < 8) stageW((tap + 1) & 1, tap + 1);   // rides under this tap

        const int ky = tap / 3, kx = tap - (tap / 3) * 3;
        int abyte[4], akey[4];
        #pragma unroll
        for (int i = 0; i < 4; ++i) {
            const int hp = (pr[i] + ky) * 10 + pc[i] + kx;
            abyte[i] = hp * 256;
            akey[i] = (hp & 7) << 4;
        }
        const char* bufp = (const char*)&sWs[tap & 1][0];

        #pragma unroll
        for (int kk = 0; kk < 3; ++kk) {
            short8 b[3];
            #pragma unroll
            for (int n = 0; n < 3; ++n) {
                const int A = brow0 + n * 4096 + kk * 64;   // n*16 rows * 256 B
                b[n] = *(const short8*)(bufp + (A ^ bkey));
            }
            short8 a[4];
            #pragma unroll
            for (int i = 0; i < 4; ++i) {
                const int s = (kk * 64 + lq * 16) ^ akey[i];
                a[i] = *(const short8*)((const char*)sH + abyte[i] + s);
            }
            #pragma unroll
            for (int i = 0; i < 4; ++i)
                #pragma unroll
                for (int n = 0; n < 3; ++n)
                    acc[i][n] = __builtin_amdgcn_mfma_f32_16x16x32_bf16(
                        a[i], b[n], acc[i][n], 0, 0, 0);
        }
        __syncthreads();   // drains slab t+1 (vmcnt) + releases buf readers
    }

    // ---- epilogue: bias (conv_b + sum Bt, border-corrected) + silu ----
    float* sY = (float*)sH;              // 64 px * 100 dw (sH dead)
    float bt[3][9];
    #pragma unroll
    for (int n = 0; n < 3; ++n)
        #pragma unroll
        for (int d2 = 0; d2 < 9; ++d2)
            bt[n][d2] = g_Bt[d2 * 96 + w * 48 + n * 16 + lm];
    float bvn[3];
    #pragma unroll
    for (int n = 0; n < 3; ++n) {
        float sum = conv_b[w * 48 + n * 16 + lm];
        #pragma unroll
        for (int d2 = 0; d2 < 9; ++d2) sum += bt[n][d2];
        bvn[n] = sum;
    }

    const bool borderTile = (ty == 0) || (ty == 48) || (tx == 0) || (tx == 48);

    #pragma unroll
    for (int i = 0; i < 4; ++i)
        #pragma unroll
        for (int r4 = 0; r4 < 4; ++r4) {
            const int p = i * 16 + lq * 4 + r4;
            const int grow = ty + (p >> 3), gcol = tx + (p & 7);
            float corr[3] = {0.f, 0.f, 0.f};
            if (borderTile) {
                #pragma unroll
                for (int dy = 0; dy < 3; ++dy)
                    #pragma unroll
                    for (int dx = 0; dx < 3; ++dx) {
                        const int gr2 = grow + dy - 1, gc2 = gcol + dx - 1;
                        if (gr2 < 0 || gr2 >= HH || gc2 < 0 || gc2 >= WW) {
                            corr[0] += bt[0][dy * 3 + dx];
                            corr[1] += bt[1][dy * 3 + dx];
                            corr[2] += bt[2][dy * 3 + dx];
                        }
                    }
            }
            #pragma unroll
            for (int n = 0; n < 3; ++n) {
                const float y = acc[i][n][r4] + bvn[n] - corr[n];
                const float sig = 1.f / (1.f + __expf(-y));
                sY[p * 100 + w * 48 + n * 16 + lm] = y * sig;
            }
        }
    __syncthreads();

    #pragma unroll
    for (int c = 0; c < 12; ++c) {
        const int d = c * 512 + t * 4;                 // < 6144
        const int px = d / 96, b = d - px * 96;
        const int grow = ty + (px >> 3), gcol = tx + (px & 7);
        const size_t gdw = (imgbase + grow * WW + gcol) * 96 + b;
        const f32x4 yv = *(const f32x4*)(sY + px * 100 + b);
        const float4 xv = *(const float4*)(X + gdw);
        float4 o;
        o.x = xv.x + yv[0]; o.y = xv.y + yv[1];
        o.z = xv.z + yv[2]; o.w = xv.w + yv[3];
        *(float4*)(OUT + gdw) = o;
    }
}

extern "C" void kernel_launch(void* const* d_in, const int* in_sizes, int n_in,
                              void* d_out, int out_size, void* d_ws, size_t ws_size,
                              hipStream_t stream) {
    (void)in_sizes; (void)n_in; (void)out_size; (void)d_ws; (void)ws_size;
    const float* X    = (const float*)d_in[0];
    const float* ln_w = (const float*)d_in[1];
    const float* ln_b = (const float*)d_in[2];
    const float* Wi   = (const float*)d_in[3];
    const float* b_in = (const float*)d_in[4];
    const float* Wc   = (const float*)d_in[5];
    const float* cb   = (const float*)d_in[6];
    float* OUT = (float*)d_out;

    k0_wt<<<(9 * WSLAB + 864 + 255) / 256, 256, 0, stream>>>(Wc, Wi, b_in);
    k_fused<<<K2_NWG, 128, 0, stream>>>(X, ln_w, ln_b, cb, OUT);
}

// Round 31
// 72.513 us; speedup vs baseline: 1.1353x; 1.1353x over previous
//
#include <hip/hip_runtime.h>
#include <hip/hip_bf16.h>

#define D_MODEL 96
#define D_INNER 192
#define BATCH 32
#define HH 56
#define WW 56
#define NPIX (BATCH*HH*WW)   // 100352
#define LN_EPS 1e-5f
#define WSLAB 12288          // shorts per combined tap slab (96 oc * 128 pad)
#define WSLABB 24576         // bytes
#define K2_NWG 1568          // NPIX / 64 = 8 * 196 (bijective XCD swizzle)
#define K2_CPX 196

typedef unsigned short ushort_t;
typedef __attribute__((ext_vector_type(8))) short short8;   // 8 bf16 (4 VGPRs)
typedef __attribute__((ext_vector_type(4))) float f32x4;

// g_Wcomb[tap][oc][s]: combined (Wi_live @ Wc[tap]) bf16, 256-B rows,
// pre-swizzled by short-index XOR ((oc&7)<<3) (r27-verified).
// g_Bt[tap][oc] = b_in @ Wc[tap] (fp32).
__device__ __align__(16) ushort_t g_Wcomb[9 * WSLAB];
__device__ float g_Bt[9 * 96];

static __device__ __forceinline__ unsigned short f2bf(float f) {
    unsigned u = __float_as_uint(f);
    unsigned r = (u + 0x7fffu + ((u >> 16) & 1u)) >> 16;
    return (unsigned short)r;
}

// ---------------------------------------------------------------------------
// Kernel 0: weight fold (r29-verified: 4 independent accumulators).
// ---------------------------------------------------------------------------
__global__ __launch_bounds__(256) void k0_wt(const float* __restrict__ Wc,
                                             const float* __restrict__ Wi,
                                             const float* __restrict__ b_in) {
    __shared__ float sWi[96 * 193];   // 74,112 B
    const int t = threadIdx.x;
    for (int i = t; i < 96 * 192; i += 256) {
        const int c = i / 192, j = i - c * 192;
        sWi[c * 193 + j] = Wi[c * 384 + j];
    }
    __syncthreads();

    const int o = blockIdx.x * 256 + t;
    if (o < 9 * WSLAB) {
        const int tap = o / WSLAB;
        const int rem = o - tap * WSLAB;
        const int oc = rem >> 7, s = rem & 127;
        const int sl = s ^ ((oc & 7) << 3);          // logical c index
        float acc = 0.f;
        if (sl < 96) {
            const float* wi = sWi + sl * 193;
            const float* wc = Wc + (size_t)tap * 18432 + oc;
            float a0 = 0.f, a1 = 0.f, a2 = 0.f, a3 = 0.f;
            #pragma unroll 8
            for (int j = 0; j < 192; j += 4) {
                a0 += wi[j + 0] * wc[(j + 0) * 96];
                a1 += wi[j + 1] * wc[(j + 1) * 96];
                a2 += wi[j + 2] * wc[(j + 2) * 96];
                a3 += wi[j + 3] * wc[(j + 3) * 96];
            }
            acc = (a0 + a1) + (a2 + a3);
        }
        g_Wcomb[o] = f2bf(acc);
    } else if (o < 9 * WSLAB + 864) {
        const int idx = o - 9 * WSLAB;
        const int tap = idx / 96, oc = idx - tap * 96;
        const float* wc = Wc + (size_t)tap * 18432 + oc;
        float a0 = 0.f, a1 = 0.f, a2 = 0.f, a3 = 0.f;
        #pragma unroll 8
        for (int j = 0; j < 192; j += 4) {
            a0 += b_in[j + 0] * wc[(j + 0) * 96];
            a1 += b_in[j + 1] * wc[(j + 1) * 96];
            a2 += b_in[j + 2] * wc[(j + 2) * 96];
            a3 += b_in[j + 3] * wc[(j + 3) * 96];
        }
        g_Bt[idx] = (a0 + a1) + (a2 + a3);
    }
}

// ---------------------------------------------------------------------------
// FUSED kernel: LN (halo recompute) + folded conv + bias + SiLU + residual.
// FINAL = round-29 verified version (72.6 us total, absmax 0.03125).
// Single-buffered slab (50.2 KB LDS -> 3 blocks/CU); r30's double-buffer
// variant dropped to 2 blocks/CU and regressed (78.5 us) -> reverted.
// ---------------------------------------------------------------------------
__global__ __launch_bounds__(128) void k_fused(
    const float* __restrict__ X, const float* __restrict__ ln_w,
    const float* __restrict__ ln_b, const float* __restrict__ conv_b,
    float* __restrict__ OUT)
{
    __shared__ ushort_t sH[100 * 128];   // 25,600 B halo h (swizzled rows)
    __shared__ ushort_t sWs[WSLAB];      // 24,576 B tap slab (pre-swizzled)
    const int t = threadIdx.x;
    const int w = t >> 6, l = t & 63;
    const int lm = l & 15, lq = l >> 4;

    const int lb = ((int)blockIdx.x & 7) * K2_CPX + ((int)blockIdx.x >> 3);
    const int img = lb / 49, tile = lb - img * 49;
    const int ty = (tile / 7) * 8, tx = (tile % 7) * 8;
    const size_t imgbase = (size_t)img * 3136;

    // ---- W staging: linear async copy (r27-verified) ----
    auto stageW = [&](int tap) {
        const char* g = (const char*)g_Wcomb + (size_t)tap * WSLABB + t * 16;
        char* d = (char*)sWs + t * 16;
        #pragma unroll
        for (int j = 0; j < 12; ++j)
            __builtin_amdgcn_global_load_lds(
                (const __attribute__((address_space(1))) unsigned*)(g + j * 2048),
                (__attribute__((address_space(3))) unsigned*)(d + j * 2048),
                16, 0, 0);
    };
    stageW(0);                           // overlaps Phase-1 LN

    // ================= Phase 1: LN halo -> swizzled sH ====================
    {
        const int g4 = t >> 2, tig = t & 3;
        #pragma unroll 1
        for (int it = 0; it < 4; ++it) {
            const int px = it * 32 + g4;
            if (px >= 100) continue;
            const int hr = px / 10, hc = px - hr * 10;
            const int gr = ty + hr - 1, gc = tx + hc - 1;
            const bool valid = gr >= 0 && gr < HH && gc >= 0 && gc < WW;
            const float* xp = X + (imgbase + gr * WW + gc) * 96 + tig * 24;
            uint4 out[3];
            if (valid) {
                float4 xq[6];
                float s = 0.f;
                #pragma unroll
                for (int c = 0; c < 6; ++c) {
                    xq[c] = *(const float4*)(xp + c * 4);
                    s += xq[c].x + xq[c].y + xq[c].z + xq[c].w;
                }
                s += __shfl_xor(s, 1, 4);
                s += __shfl_xor(s, 2, 4);
                const float mu = s * (1.f / 96.f);
                float v = 0.f;
                #pragma unroll
                for (int c = 0; c < 6; ++c) {
                    const float d0 = xq[c].x - mu, d1 = xq[c].y - mu;
                    const float d2 = xq[c].z - mu, d3 = xq[c].w - mu;
                    v += d0 * d0 + d1 * d1 + d2 * d2 + d3 * d3;
                }
                v += __shfl_xor(v, 1, 4);
                v += __shfl_xor(v, 2, 4);
                const float rs = rsqrtf(v * (1.f / 96.f) + LN_EPS);
                unsigned u[12];
                #pragma unroll
                for (int c = 0; c < 6; ++c) {
                    const float4 lw = *(const float4*)(ln_w + tig * 24 + c * 4);
                    const float4 lb2 = *(const float4*)(ln_b + tig * 24 + c * 4);
                    u[c * 2 + 0] = (unsigned)f2bf((xq[c].x - mu) * rs * lw.x + lb2.x)
                                 | ((unsigned)f2bf((xq[c].y - mu) * rs * lw.y + lb2.y) << 16);
                    u[c * 2 + 1] = (unsigned)f2bf((xq[c].z - mu) * rs * lw.z + lb2.z)
                                 | ((unsigned)f2bf((xq[c].w - mu) * rs * lw.w + lb2.w) << 16);
                }
                out[0] = make_uint4(u[0], u[1], u[2], u[3]);
                out[1] = make_uint4(u[4], u[5], u[6], u[7]);
                out[2] = make_uint4(u[8], u[9], u[10], u[11]);
            } else {
                out[0] = out[1] = out[2] = make_uint4(0u, 0u, 0u, 0u);
            }
            const int key = (px & 7) << 4;
            char* rowp = (char*)sH + px * 256;
            #pragma unroll
            for (int q = 0; q < 3; ++q)
                *(uint4*)(rowp + (((tig * 3 + q) * 16) ^ key)) = out[q];
        }
    }
    __syncthreads();   // sH written + tap-0 slab drained (vmcnt)

    // ========== Phase 2: conv main loop (r27/r29-verified) ================
    int pr[4], pc[4];
    #pragma unroll
    for (int i = 0; i < 4; ++i) {
        const int px = i * 16 + lm;
        pr[i] = px >> 3; pc[i] = px & 7;
    }

    f32x4 acc[4][3];
    const f32x4 zf = {0.f, 0.f, 0.f, 0.f};
    #pragma unroll
    for (int i = 0; i < 4; ++i)
        #pragma unroll
        for (int n = 0; n < 3; ++n) acc[i][n] = zf;

    const int bkey = (lm & 7) << 4;
    const int brow0 = (w * 48 + lm) * 256 + lq * 16;   // wave's oc base row

    #pragma unroll 1
    for (int tap = 0; tap < 9; ++tap) {
        const int ky = tap / 3, kx = tap - (tap / 3) * 3;
        int abyte[4], akey[4];
        #pragma unroll
        for (int i = 0; i < 4; ++i) {
            const int hp = (pr[i] + ky) * 10 + pc[i] + kx;
            abyte[i] = hp * 256;
            akey[i] = (hp & 7) << 4;
        }

        #pragma unroll
        for (int kk = 0; kk < 3; ++kk) {
            short8 b[3];
            #pragma unroll
            for (int n = 0; n < 3; ++n) {
                const int A = brow0 + n * 4096 + kk * 64;   // n*16 rows * 256 B
                b[n] = *(const short8*)((const char*)sWs + (A ^ bkey));
            }
            short8 a[4];
            #pragma unroll
            for (int i = 0; i < 4; ++i) {
                const int s = (kk * 64 + lq * 16) ^ akey[i];
                a[i] = *(const short8*)((const char*)sH + abyte[i] + s);
            }
            #pragma unroll
            for (int i = 0; i < 4; ++i)
                #pragma unroll
                for (int n = 0; n < 3; ++n)
                    acc[i][n] = __builtin_amdgcn_mfma_f32_16x16x32_bf16(
                        a[i], b[n], acc[i][n], 0, 0, 0);
        }
        __syncthreads();                 // all waves done reading sWs (+sH last tap)
        if (tap < 8) { stageW(tap + 1); __syncthreads(); }
    }

    // ---- epilogue: bias (conv_b + sum Bt, border-corrected) + silu ----
    float* sY = (float*)sH;              // 64 px * 100 dw (sH dead)
    float bt[3][9];
    #pragma unroll
    for (int n = 0; n < 3; ++n)
        #pragma unroll
        for (int d2 = 0; d2 < 9; ++d2)
            bt[n][d2] = g_Bt[d2 * 96 + w * 48 + n * 16 + lm];
    float bvn[3];
    #pragma unroll
    for (int n = 0; n < 3; ++n) {
        float sum = conv_b[w * 48 + n * 16 + lm];
        #pragma unroll
        for (int d2 = 0; d2 < 9; ++d2) sum += bt[n][d2];
        bvn[n] = sum;
    }

    const bool borderTile = (ty == 0) || (ty == 48) || (tx == 0) || (tx == 48);

    #pragma unroll
    for (int i = 0; i < 4; ++i)
        #pragma unroll
        for (int r4 = 0; r4 < 4; ++r4) {
            const int p = i * 16 + lq * 4 + r4;
            const int grow = ty + (p >> 3), gcol = tx + (p & 7);
            float corr[3] = {0.f, 0.f, 0.f};
            if (borderTile) {
                #pragma unroll
                for (int dy = 0; dy < 3; ++dy)
                    #pragma unroll
                    for (int dx = 0; dx < 3; ++dx) {
                        const int gr2 = grow + dy - 1, gc2 = gcol + dx - 1;
                        if (gr2 < 0 || gr2 >= HH || gc2 < 0 || gc2 >= WW) {
                            corr[0] += bt[0][dy * 3 + dx];
                            corr[1] += bt[1][dy * 3 + dx];
                            corr[2] += bt[2][dy * 3 + dx];
                        }
                    }
            }
            #pragma unroll
            for (int n = 0; n < 3; ++n) {
                const float y = acc[i][n][r4] + bvn[n] - corr[n];
                const float sig = 1.f / (1.f + __expf(-y));
                sY[p * 100 + w * 48 + n * 16 + lm] = y * sig;
            }
        }
    __syncthreads();

    #pragma unroll
    for (int c = 0; c < 12; ++c) {
        const int d = c * 512 + t * 4;                 // < 6144
        const int px = d / 96, b = d - px * 96;
        const int grow = ty + (px >> 3), gcol = tx + (px & 7);
        const size_t gdw = (imgbase + grow * WW + gcol) * 96 + b;
        const f32x4 yv = *(const f32x4*)(sY + px * 100 + b);
        const float4 xv = *(const float4*)(X + gdw);
        float4 o;
        o.x = xv.x + yv[0]; o.y = xv.y + yv[1];
        o.z = xv.z + yv[2]; o.w = xv.w + yv[3];
        *(float4*)(OUT + gdw) = o;
    }
}

extern "C" void kernel_launch(void* const* d_in, const int* in_sizes, int n_in,
                              void* d_out, int out_size, void* d_ws, size_t ws_size,
                              hipStream_t stream) {
    (void)in_sizes; (void)n_in; (void)out_size; (void)d_ws; (void)ws_size;
    const float* X    = (const float*)d_in[0];
    const float* ln_w = (const float*)d_in[1];
    const float* ln_b = (const float*)d_in[2];
    const float* Wi   = (const float*)d_in[3];
    const float* b_in = (const float*)d_in[4];
    const float* Wc   = (const float*)d_in[5];
    const float* cb   = (const float*)d_in[6];
    float* OUT = (float*)d_out;

    k0_wt<<<(9 * WSLAB + 864 + 255) / 256, 256, 0, stream>>>(Wc, Wi, b_in);
    k_fused<<<K2_NWG, 128, 0, stream>>>(X, ln_w, ln_b, cb, OUT);
}